// Round 1
// 1773.437 us; speedup vs baseline: 1.4581x; 1.4581x over previous
//
#include <hip/hip_runtime.h>
#include <math.h>

#define B_  32
#define S_  1024
#define D_  256
#define DS_ 64
#define M_  3
#define MD_ 192   // M*DS

// lgkmcnt-only barrier: LDS visibility without draining vmcnt (keeps global
// prefetch loads / result stores in flight across recurrence steps).
#define BAR_LGKM() asm volatile("s_waitcnt lgkmcnt(0)\n\ts_barrier" ::: "memory")

__device__ __forceinline__ float rl_f32(float v, int lane) {
    return __uint_as_float(__builtin_amdgcn_readlane(__float_as_uint(v), lane));
}

#define L2E_ 1.4426950408889634f
__device__ __forceinline__ float fast_exp(float x) { return exp2f(x * L2E_); }
// tanh(x) = 1 - 2/(exp2(2*log2e*x)+1); inf-safe at both ends.
__device__ __forceinline__ float fast_tanh(float x) {
    float t = exp2f(x * (2.0f * L2E_));
    return 1.0f - 2.0f * __builtin_amdgcn_rcpf(t + 1.0f);
}

typedef float v4f __attribute__((ext_vector_type(4)));

// ---- named-register weight block: 16 float4 = 64 floats, NO arrays --------
// asm pin: forces the 64 floats to be materialized in arch VGPRs and blocks
// the compiler from rematerializing the (restrict-const) loads inside the
// recurrence loop. (Baseline VGPR_Count=56 < 64 proves the weights were NOT
// register-resident.)
#define DECL_W16(src) \
    v4f W00 = (src)[0],  W01 = (src)[1],  W02 = (src)[2],  W03 = (src)[3],  \
        W04 = (src)[4],  W05 = (src)[5],  W06 = (src)[6],  W07 = (src)[7],  \
        W08 = (src)[8],  W09 = (src)[9],  W10 = (src)[10], W11 = (src)[11], \
        W12 = (src)[12], W13 = (src)[13], W14 = (src)[14], W15 = (src)[15]; \
    asm volatile("" : "+v"(W00), "+v"(W01), "+v"(W02), "+v"(W03));          \
    asm volatile("" : "+v"(W04), "+v"(W05), "+v"(W06), "+v"(W07));          \
    asm volatile("" : "+v"(W08), "+v"(W09), "+v"(W10), "+v"(W11));          \
    asm volatile("" : "+v"(W12), "+v"(W13), "+v"(W14), "+v"(W15));

// dot of the 64 named weights with lanes of hreg (readlane broadcast)
#define DOT4_RL(Wv, k0) \
    a0 = fmaf(Wv.x, rl_f32(hreg, (k0) + 0), a0); \
    a1 = fmaf(Wv.y, rl_f32(hreg, (k0) + 1), a1); \
    a2 = fmaf(Wv.z, rl_f32(hreg, (k0) + 2), a2); \
    a3 = fmaf(Wv.w, rl_f32(hreg, (k0) + 3), a3);
#define DOT64_RL() \
    DOT4_RL(W00, 0)  DOT4_RL(W01, 4)  DOT4_RL(W02, 8)  DOT4_RL(W03, 12) \
    DOT4_RL(W04, 16) DOT4_RL(W05, 20) DOT4_RL(W06, 24) DOT4_RL(W07, 28) \
    DOT4_RL(W08, 32) DOT4_RL(W09, 36) DOT4_RL(W10, 40) DOT4_RL(W11, 44) \
    DOT4_RL(W12, 48) DOT4_RL(W13, 52) DOT4_RL(W14, 56) DOT4_RL(W15, 60)

// dot of the 64 named weights with a v4f* (LDS) vector
#define DOT4_V(Wv, hv) \
    a0 = fmaf(Wv.x, (hv).x, a0); \
    a1 = fmaf(Wv.y, (hv).y, a1); \
    a2 = fmaf(Wv.z, (hv).z, a2); \
    a3 = fmaf(Wv.w, (hv).w, a3);
#define DOT64_V(h4) \
    DOT4_V(W00, (h4)[0])  DOT4_V(W01, (h4)[1])  DOT4_V(W02, (h4)[2])  DOT4_V(W03, (h4)[3])  \
    DOT4_V(W04, (h4)[4])  DOT4_V(W05, (h4)[5])  DOT4_V(W06, (h4)[6])  DOT4_V(W07, (h4)[7])  \
    DOT4_V(W08, (h4)[8])  DOT4_V(W09, (h4)[9])  DOT4_V(W10, (h4)[10]) DOT4_V(W11, (h4)[11]) \
    DOT4_V(W12, (h4)[12]) DOT4_V(W13, (h4)[13]) DOT4_V(W14, (h4)[14]) DOT4_V(W15, (h4)[15])

// ---------------------------------------------------------------------------
// Kernel 1: xp[b][t][m*64+d] = Xb[m][d] + sum_k XW[m][d][k] * x_m[b][t][k]
// ---------------------------------------------------------------------------
__global__ __launch_bounds__(256, 2)
void k1_xproj(const float* __restrict__ xa, const float* __restrict__ xv,
              const float* __restrict__ xl, const float* __restrict__ XW,
              const float* __restrict__ Xb, float* __restrict__ xp)
{
    const int m  = blockIdx.z;
    const int b  = blockIdx.y;
    const int t0 = blockIdx.x * 128;
    const float* __restrict__ xm = (m == 0) ? xa : ((m == 1) ? xv : xl);
    const int tid = threadIdx.x;
    const int q = tid >> 6;
    const int d = tid & 63;

    __shared__ __align__(16) float xs[4][256];
    __shared__ float part[4][4][64];

    const v4f* wsrc = reinterpret_cast<const v4f*>(XW + ((m * 64 + d) * 256 + q * 64));
    DECL_W16(wsrc);
    const float xbv = Xb[m * 64 + d];

    for (int g = 0; g < 32; ++g) {
        const int tb = t0 + g * 4;
        {
            const float* src = xm + ((size_t)b * S_ + tb) * D_;
            xs[0][tid] = src[0 * 256 + tid];
            xs[1][tid] = src[1 * 256 + tid];
            xs[2][tid] = src[2 * 256 + tid];
            xs[3][tid] = src[3 * 256 + tid];
        }
        __syncthreads();
        #pragma unroll
        for (int tt = 0; tt < 4; ++tt) {
            const v4f* xq = reinterpret_cast<const v4f*>(&xs[tt][q * 64]);
            float a0 = 0.f, a1 = 0.f, a2 = 0.f, a3 = 0.f;
            DOT64_V(xq);
            part[tt][q][d] = (a0 + a1) + (a2 + a3);
        }
        __syncthreads();
        {
            const int tt = q;
            float ssum = part[tt][0][d] + part[tt][1][d] + part[tt][2][d] + part[tt][3][d] + xbv;
            xp[((size_t)b * S_ + tb + tt) * MD_ + m * 64 + d] = ssum;
        }
    }
}

// ---------------------------------------------------------------------------
// Kernel 2 v4: recurrence. 32 blocks x 768 threads (12 waves), TWO lgkm-only
// barriers per step:
//   phase A (all 12 waves): one 64-deep dot each, weights pinned in VGPRs.
//     waves 0..8  (w=3m+s): su/coupling parts (HW diag, CW off-diag)
//     waves 9..11 (g):      gate parts (W1 column-slice g)
//   BAR1 -> gate wave g (== tgt modality m) does EVERYTHING for its modality:
//     z=tanh(sum of gate parts + b1); 3 W2-row dots via 4-level butterfly +
//     4 readlanes (uniform result, never touches LDS); uniform softmax;
//     combine with su parts + x_t + Hb; silu; write h into double buffer;
//     prefetch x_{t+1}; batched hbuf store every 4 steps.
//   BAR2 -> next step.
// attn stays in SGPRs: no attnsh buffer, no owner phase, no third barrier.
// ---------------------------------------------------------------------------
__global__ __launch_bounds__(768, 1)
void k2_recur(const float* __restrict__ xp, float* __restrict__ hbuf,
              const float* __restrict__ HW, const float* __restrict__ Hb,
              const float* __restrict__ CW, const float* __restrict__ W1,
              const float* __restrict__ b1, const float* __restrict__ W2,
              const float* __restrict__ b2)
{
    const int b    = blockIdx.x;
    const int tid  = threadIdx.x;
    const int w    = tid >> 6;
    const int lane = tid & 63;

    const bool is_gate = (w >= 9);
    const int  m = is_gate ? (w - 9) : (w / 3);   // gate wave g owns tgt m=g
    const int  s = is_gate ? (w - 9) : (w % 3);   // broadcast-source h segment

    __shared__ __align__(16) float hds[2][MD_];
    __shared__ float parts[12][64];

    if (tid < MD_) hds[0][tid] = 0.f;

    // ---- weights: 16 pinned float4 registers per lane ----
    const float* base;
    if (!is_gate) base = (s == m) ? (HW + (m * 64 + lane) * 64)
                                  : (CW + (((m * 3 + s) * 64) + lane) * 64);
    else          base = W1 + lane * MD_ + m * 64;
    const v4f* wsrc = reinterpret_cast<const v4f*>(base);
    DECL_W16(wsrc);

    // gate-wave constants
    float hbv = 0.f, b1v = 0.f;
    float w2r0 = 0.f, w2r1 = 0.f, w2r2 = 0.f, b2v0 = 0.f, b2v1 = 0.f, b2v2 = 0.f;
    float xnext = 0.f;
    if (is_gate) {
        hbv  = Hb[m * 64 + lane];
        b1v  = b1[lane];
        w2r0 = W2[(m * 3 + 0) * 64 + lane];
        w2r1 = W2[(m * 3 + 1) * 64 + lane];
        w2r2 = W2[(m * 3 + 2) * 64 + lane];
        b2v0 = b2[m * 3 + 0]; b2v1 = b2[m * 3 + 1]; b2v2 = b2[m * 3 + 2];
        xnext = xp[((size_t)b * S_) * MD_ + m * 64 + lane];
    }
    const int s1 = (m + 1) % 3, s2 = (m + 2) % 3;
    float hist0 = 0.f, hist1 = 0.f, hist2 = 0.f, hist3 = 0.f;

    __syncthreads();

    for (int t = 0; t < S_; ++t) {
        const int cur = t & 1, nxt = cur ^ 1;

        // ---- phase A: every wave one 64-deep dot, weights in registers ----
        float hreg = hds[cur][s * 64 + lane];
        float a0 = 0.f, a1 = 0.f, a2 = 0.f, a3 = 0.f;
        DOT64_RL();
        parts[w][lane] = (a0 + a1) + (a2 + a3);
        BAR_LGKM();   // all partials visible

        // ---- gate wave m: tail + combine + state update, all local ----
        if (is_gate) {
            const float xv = xnext;
            if (t + 1 < S_)
                xnext = xp[((size_t)b * S_ + t + 1) * MD_ + m * 64 + lane];

            // issue LDS reads early; latency hides under tanh/butterfly
            float pm  = parts[m * 3 + m][lane];
            float pc1 = parts[m * 3 + s1][lane];
            float pc2 = parts[m * 3 + s2][lane];
            float g0  = parts[9][lane];
            float g1  = parts[10][lane];
            float g2  = parts[11][lane];

            float z = fast_tanh(b1v + g0 + g1 + g2);
            float p0 = w2r0 * z, p1 = w2r1 * z, p2 = w2r2 * z;
            #pragma unroll
            for (int off = 1; off <= 8; off <<= 1) {
                p0 += __shfl_xor(p0, off);
                p1 += __shfl_xor(p1, off);
                p2 += __shfl_xor(p2, off);
            }
            // per-16-lane-group sums -> uniform totals via readlane
            float r0 = b2v0 + ((rl_f32(p0, 0)  + rl_f32(p0, 16)) +
                               (rl_f32(p0, 32) + rl_f32(p0, 48)));
            float r1 = b2v1 + ((rl_f32(p1, 0)  + rl_f32(p1, 16)) +
                               (rl_f32(p1, 32) + rl_f32(p1, 48)));
            float r2 = b2v2 + ((rl_f32(p2, 0)  + rl_f32(p2, 16)) +
                               (rl_f32(p2, 32) + rl_f32(p2, 48)));
            // uniform softmax over this wave's own attn row (tgt = m)
            float mx  = fmaxf(r0, fmaxf(r1, r2));
            float e0  = fast_exp(r0 - mx);
            float e1  = fast_exp(r1 - mx);
            float e2  = fast_exp(r2 - mx);
            float inv = __builtin_amdgcn_rcpf(e0 + e1 + e2);
            float a1v = ((s1 == 1) ? e1 : (s1 == 2) ? e2 : e0) * inv;
            float a2v = ((s2 == 1) ? e1 : (s2 == 2) ? e2 : e0) * inv;

            float suv = xv + hbv + pm + a1v * pc1 + a2v * pc2;
            float hn  = suv * __builtin_amdgcn_rcpf(1.f + fast_exp(-suv));
            hds[nxt][m * 64 + lane] = hn;

            if      ((t & 3) == 0) hist0 = hn;
            else if ((t & 3) == 1) hist1 = hn;
            else if ((t & 3) == 2) hist2 = hn;
            else {
                hist3 = hn;
                float* dst = hbuf + ((size_t)b * S_ + (t - 3)) * MD_ + m * 64 + lane;
                dst[0 * MD_] = hist0; dst[1 * MD_] = hist1;
                dst[2 * MD_] = hist2; dst[3 * MD_] = hist3;
            }
        }
        BAR_LGKM();   // h_new visible
    }
}

// ---------------------------------------------------------------------------
// Kernel 3: out = LayerNorm(Ob + OW@h + x); OW row in pinned registers.
// ---------------------------------------------------------------------------
__global__ __launch_bounds__(256, 2)
void k3_out(const float* __restrict__ xa, const float* __restrict__ xv,
            const float* __restrict__ xl, const float* __restrict__ hbuf,
            const float* __restrict__ OW, const float* __restrict__ Ob,
            const float* __restrict__ lng, const float* __restrict__ lnb,
            float* __restrict__ out)
{
    const int m  = blockIdx.z;
    const int b  = blockIdx.y;
    const int t0 = blockIdx.x * 128;
    const float* __restrict__ xm = (m == 0) ? xa : ((m == 1) ? xv : xl);
    const int k    = threadIdx.x;
    const int wv   = k >> 6;
    const int lane = k & 63;

    __shared__ __align__(16) float hs[4 * 64];
    __shared__ float psum[16], qsum[16];

    const v4f* wsrc = reinterpret_cast<const v4f*>(OW + (m * D_ + k) * DS_);
    DECL_W16(wsrc);
    const float obv = Ob[m * D_ + k];
    const float gv  = lng[m * D_ + k];
    const float bv  = lnb[m * D_ + k];

    for (int gg = 0; gg < 32; ++gg) {
        const int tb = t0 + gg * 4;
        hs[k] = hbuf[((size_t)b * S_ + tb + (k >> 6)) * MD_ + m * 64 + (k & 63)];
        __syncthreads();

        float v0, v1, v2, v3;
        {
            const v4f* h4 = reinterpret_cast<const v4f*>(&hs[0]);
            float a0 = 0.f, a1 = 0.f, a2 = 0.f, a3 = 0.f;
            DOT64_V(h4);
            v0 = obv + (a0 + a1) + (a2 + a3) + xm[((size_t)b * S_ + tb + 0) * D_ + k];
        }
        {
            const v4f* h4 = reinterpret_cast<const v4f*>(&hs[64]);
            float a0 = 0.f, a1 = 0.f, a2 = 0.f, a3 = 0.f;
            DOT64_V(h4);
            v1 = obv + (a0 + a1) + (a2 + a3) + xm[((size_t)b * S_ + tb + 1) * D_ + k];
        }
        {
            const v4f* h4 = reinterpret_cast<const v4f*>(&hs[128]);
            float a0 = 0.f, a1 = 0.f, a2 = 0.f, a3 = 0.f;
            DOT64_V(h4);
            v2 = obv + (a0 + a1) + (a2 + a3) + xm[((size_t)b * S_ + tb + 2) * D_ + k];
        }
        {
            const v4f* h4 = reinterpret_cast<const v4f*>(&hs[192]);
            float a0 = 0.f, a1 = 0.f, a2 = 0.f, a3 = 0.f;
            DOT64_V(h4);
            v3 = obv + (a0 + a1) + (a2 + a3) + xm[((size_t)b * S_ + tb + 3) * D_ + k];
        }

        float s0 = v0, s1v = v1, s2v = v2, s3 = v3;
        float q0 = v0 * v0, q1 = v1 * v1, q2 = v2 * v2, q3 = v3 * v3;
        #pragma unroll
        for (int off = 32; off >= 1; off >>= 1) {
            s0  += __shfl_down(s0, off);  s1v += __shfl_down(s1v, off);
            s2v += __shfl_down(s2v, off); s3  += __shfl_down(s3, off);
            q0  += __shfl_down(q0, off);  q1  += __shfl_down(q1, off);
            q2  += __shfl_down(q2, off);  q3  += __shfl_down(q3, off);
        }
        if (lane == 0) {
            psum[wv * 4 + 0] = s0;  psum[wv * 4 + 1] = s1v;
            psum[wv * 4 + 2] = s2v; psum[wv * 4 + 3] = s3;
            qsum[wv * 4 + 0] = q0;  qsum[wv * 4 + 1] = q1;
            qsum[wv * 4 + 2] = q2;  qsum[wv * 4 + 3] = q3;
        }
        __syncthreads();

        const size_t obase = (size_t)m * ((size_t)B_ * S_ * D_) + ((size_t)b * S_ + tb) * D_ + k;
        {
            float ss = psum[0] + psum[4] + psum[8] + psum[12];
            float qq = qsum[0] + qsum[4] + qsum[8] + qsum[12];
            float mu = ss * (1.f / 256.f);
            float var = qq * (1.f / 256.f) - mu * mu;
            float rs = rsqrtf(var + 1e-5f);
            out[obase + 0 * D_] = (v0 - mu) * rs * gv + bv;
        }
        {
            float ss = psum[1] + psum[5] + psum[9] + psum[13];
            float qq = qsum[1] + qsum[5] + qsum[9] + qsum[13];
            float mu = ss * (1.f / 256.f);
            float var = qq * (1.f / 256.f) - mu * mu;
            float rs = rsqrtf(var + 1e-5f);
            out[obase + 1 * D_] = (v1 - mu) * rs * gv + bv;
        }
        {
            float ss = psum[2] + psum[6] + psum[10] + psum[14];
            float qq = qsum[2] + qsum[6] + qsum[10] + qsum[14];
            float mu = ss * (1.f / 256.f);
            float var = qq * (1.f / 256.f) - mu * mu;
            float rs = rsqrtf(var + 1e-5f);
            out[obase + 2 * D_] = (v2 - mu) * rs * gv + bv;
        }
        {
            float ss = psum[3] + psum[7] + psum[11] + psum[15];
            float qq = qsum[3] + qsum[7] + qsum[11] + qsum[15];
            float mu = ss * (1.f / 256.f);
            float var = qq * (1.f / 256.f) - mu * mu;
            float rs = rsqrtf(var + 1e-5f);
            out[obase + 3 * D_] = (v3 - mu) * rs * gv + bv;
        }
    }
}

extern "C" void kernel_launch(void* const* d_in, const int* in_sizes, int n_in,
                              void* d_out, int out_size, void* d_ws, size_t ws_size,
                              hipStream_t stream)
{
    const float* xa  = (const float*)d_in[0];
    const float* xv  = (const float*)d_in[1];
    const float* xl  = (const float*)d_in[2];
    const float* XW  = (const float*)d_in[3];
    const float* Xb  = (const float*)d_in[4];
    const float* HW  = (const float*)d_in[5];
    const float* Hb  = (const float*)d_in[6];
    const float* OW  = (const float*)d_in[7];
    const float* Ob  = (const float*)d_in[8];
    const float* CW  = (const float*)d_in[9];
    const float* W1  = (const float*)d_in[10];
    const float* b1  = (const float*)d_in[11];
    const float* W2  = (const float*)d_in[12];
    const float* b2  = (const float*)d_in[13];
    const float* lng = (const float*)d_in[14];
    const float* lnb = (const float*)d_in[15];
    float* out = (float*)d_out;

    float* xp = (float*)d_ws;                          // [B][S][192]
    float* hb = xp + (size_t)B_ * S_ * MD_;            // [B][S][192]

    k1_xproj<<<dim3(8, 32, 3), 256, 0, stream>>>(xa, xv, xl, XW, Xb, xp);
    k2_recur<<<dim3(32), 768, 0, stream>>>(xp, hb, HW, Hb, CW, W1, b1, W2, b2);
    k3_out  <<<dim3(8, 32, 3), 256, 0, stream>>>(xa, xv, xl, hb, OW, Ob, lng, lnb, out);
}

// Round 2
// 1338.933 us; speedup vs baseline: 1.9312x; 1.3245x over previous
//
#include <hip/hip_runtime.h>
#include <math.h>

#define B_  32
#define S_  1024
#define D_  256
#define DS_ 64
#define M_  3
#define MD_ 192   // M*DS

// lgkmcnt-only barrier: LDS visibility without draining vmcnt (keeps global
// prefetch loads / result stores in flight across recurrence steps).
#define BAR_LGKM() asm volatile("s_waitcnt lgkmcnt(0)\n\ts_barrier" ::: "memory")

__device__ __forceinline__ float rl_f32(float v, int lane) {
    return __uint_as_float(__builtin_amdgcn_readlane(__float_as_uint(v), lane));
}

#define L2E_ 1.4426950408889634f
__device__ __forceinline__ float fast_exp(float x) { return exp2f(x * L2E_); }
// tanh(x) = 1 - 2/(exp2(2*log2e*x)+1); inf-safe at both ends.
__device__ __forceinline__ float fast_tanh(float x) {
    float t = exp2f(x * (2.0f * L2E_));
    return 1.0f - 2.0f * __builtin_amdgcn_rcpf(t + 1.0f);
}

typedef float v4f __attribute__((ext_vector_type(4)));

// ---- weight block: 16 float4 loaded via ASM so they are NOT rematerializable
// (round-1 lesson: plain loads + empty asm pin -> compiler re-loads them every
// loop iteration; VGPR_Count stayed 56 < 64 weight floats). Asm-defined values
// must stay register-resident. Our extra vmcnt-counted loads only make the
// compiler's own vmcnt(N) waits stricter (vmcnt waits "until <= N
// outstanding"), and we drain vmcnt(0) before first use.
#define ALD4(dst, p, off) \
    asm volatile("global_load_dwordx4 %0, %1, off offset:" #off \
                 : "=v"(dst) : "v"(p))

#define DECL_W16A(baseptr) \
    v4f W00, W01, W02, W03, W04, W05, W06, W07, \
        W08, W09, W10, W11, W12, W13, W14, W15; \
    { const float* _wp = (baseptr); \
      ALD4(W00, _wp, 0);   ALD4(W01, _wp, 16);  ALD4(W02, _wp, 32);  ALD4(W03, _wp, 48);  \
      ALD4(W04, _wp, 64);  ALD4(W05, _wp, 80);  ALD4(W06, _wp, 96);  ALD4(W07, _wp, 112); \
      ALD4(W08, _wp, 128); ALD4(W09, _wp, 144); ALD4(W10, _wp, 160); ALD4(W11, _wp, 176); \
      ALD4(W12, _wp, 192); ALD4(W13, _wp, 208); ALD4(W14, _wp, 224); ALD4(W15, _wp, 240); \
      asm volatile("s_waitcnt vmcnt(0)" ::: "memory"); }

// dot of the 64 named weights with lanes of hreg (readlane broadcast)
#define DOT4_RL(Wv, k0) \
    a0 = fmaf(Wv.x, rl_f32(hreg, (k0) + 0), a0); \
    a1 = fmaf(Wv.y, rl_f32(hreg, (k0) + 1), a1); \
    a2 = fmaf(Wv.z, rl_f32(hreg, (k0) + 2), a2); \
    a3 = fmaf(Wv.w, rl_f32(hreg, (k0) + 3), a3);
#define DOT64_RL() \
    DOT4_RL(W00, 0)  DOT4_RL(W01, 4)  DOT4_RL(W02, 8)  DOT4_RL(W03, 12) \
    DOT4_RL(W04, 16) DOT4_RL(W05, 20) DOT4_RL(W06, 24) DOT4_RL(W07, 28) \
    DOT4_RL(W08, 32) DOT4_RL(W09, 36) DOT4_RL(W10, 40) DOT4_RL(W11, 44) \
    DOT4_RL(W12, 48) DOT4_RL(W13, 52) DOT4_RL(W14, 56) DOT4_RL(W15, 60)

// dot of the 64 named weights with a v4f* (LDS) vector
#define DOT4_V(Wv, hv) \
    a0 = fmaf(Wv.x, (hv).x, a0); \
    a1 = fmaf(Wv.y, (hv).y, a1); \
    a2 = fmaf(Wv.z, (hv).z, a2); \
    a3 = fmaf(Wv.w, (hv).w, a3);
#define DOT64_V(h4) \
    DOT4_V(W00, (h4)[0])  DOT4_V(W01, (h4)[1])  DOT4_V(W02, (h4)[2])  DOT4_V(W03, (h4)[3])  \
    DOT4_V(W04, (h4)[4])  DOT4_V(W05, (h4)[5])  DOT4_V(W06, (h4)[6])  DOT4_V(W07, (h4)[7])  \
    DOT4_V(W08, (h4)[8])  DOT4_V(W09, (h4)[9])  DOT4_V(W10, (h4)[10]) DOT4_V(W11, (h4)[11]) \
    DOT4_V(W12, (h4)[12]) DOT4_V(W13, (h4)[13]) DOT4_V(W14, (h4)[14]) DOT4_V(W15, (h4)[15])

// ---- canonical GCN full-wave (64-lane) sum reduce via DPP; result lane 63.
// Replaces shfl_xor butterflies (DS ops, ~30-40cy latency each) with VALU adds.
#define DPP_RED3(A, Bv, C) asm volatile( \
    "v_add_f32 %0, %0, %0 row_shr:1 bound_ctrl:0\n\t" \
    "v_add_f32 %1, %1, %1 row_shr:1 bound_ctrl:0\n\t" \
    "v_add_f32 %2, %2, %2 row_shr:1 bound_ctrl:0\n\t" \
    "v_add_f32 %0, %0, %0 row_shr:2 bound_ctrl:0\n\t" \
    "v_add_f32 %1, %1, %1 row_shr:2 bound_ctrl:0\n\t" \
    "v_add_f32 %2, %2, %2 row_shr:2 bound_ctrl:0\n\t" \
    "v_add_f32 %0, %0, %0 row_shr:4 bound_ctrl:0\n\t" \
    "v_add_f32 %1, %1, %1 row_shr:4 bound_ctrl:0\n\t" \
    "v_add_f32 %2, %2, %2 row_shr:4 bound_ctrl:0\n\t" \
    "v_add_f32 %0, %0, %0 row_shr:8 bound_ctrl:0\n\t" \
    "v_add_f32 %1, %1, %1 row_shr:8 bound_ctrl:0\n\t" \
    "v_add_f32 %2, %2, %2 row_shr:8 bound_ctrl:0\n\t" \
    "v_add_f32 %0, %0, %0 row_bcast:15 row_mask:0xa\n\t" \
    "v_add_f32 %1, %1, %1 row_bcast:15 row_mask:0xa\n\t" \
    "v_add_f32 %2, %2, %2 row_bcast:15 row_mask:0xa\n\t" \
    "v_add_f32 %0, %0, %0 row_bcast:31 row_mask:0xc\n\t" \
    "v_add_f32 %1, %1, %1 row_bcast:31 row_mask:0xc\n\t" \
    "v_add_f32 %2, %2, %2 row_bcast:31 row_mask:0xc" \
    : "+v"(A), "+v"(Bv), "+v"(C))

#define DPP_RED4(A, Bv, C, Dv) asm volatile( \
    "v_add_f32 %0, %0, %0 row_shr:1 bound_ctrl:0\n\t" \
    "v_add_f32 %1, %1, %1 row_shr:1 bound_ctrl:0\n\t" \
    "v_add_f32 %2, %2, %2 row_shr:1 bound_ctrl:0\n\t" \
    "v_add_f32 %3, %3, %3 row_shr:1 bound_ctrl:0\n\t" \
    "v_add_f32 %0, %0, %0 row_shr:2 bound_ctrl:0\n\t" \
    "v_add_f32 %1, %1, %1 row_shr:2 bound_ctrl:0\n\t" \
    "v_add_f32 %2, %2, %2 row_shr:2 bound_ctrl:0\n\t" \
    "v_add_f32 %3, %3, %3 row_shr:2 bound_ctrl:0\n\t" \
    "v_add_f32 %0, %0, %0 row_shr:4 bound_ctrl:0\n\t" \
    "v_add_f32 %1, %1, %1 row_shr:4 bound_ctrl:0\n\t" \
    "v_add_f32 %2, %2, %2 row_shr:4 bound_ctrl:0\n\t" \
    "v_add_f32 %3, %3, %3 row_shr:4 bound_ctrl:0\n\t" \
    "v_add_f32 %0, %0, %0 row_shr:8 bound_ctrl:0\n\t" \
    "v_add_f32 %1, %1, %1 row_shr:8 bound_ctrl:0\n\t" \
    "v_add_f32 %2, %2, %2 row_shr:8 bound_ctrl:0\n\t" \
    "v_add_f32 %3, %3, %3 row_shr:8 bound_ctrl:0\n\t" \
    "v_add_f32 %0, %0, %0 row_bcast:15 row_mask:0xa\n\t" \
    "v_add_f32 %1, %1, %1 row_bcast:15 row_mask:0xa\n\t" \
    "v_add_f32 %2, %2, %2 row_bcast:15 row_mask:0xa\n\t" \
    "v_add_f32 %3, %3, %3 row_bcast:15 row_mask:0xa\n\t" \
    "v_add_f32 %0, %0, %0 row_bcast:31 row_mask:0xc\n\t" \
    "v_add_f32 %1, %1, %1 row_bcast:31 row_mask:0xc\n\t" \
    "v_add_f32 %2, %2, %2 row_bcast:31 row_mask:0xc\n\t" \
    "v_add_f32 %3, %3, %3 row_bcast:31 row_mask:0xc" \
    : "+v"(A), "+v"(Bv), "+v"(C), "+v"(Dv))

// ---------------------------------------------------------------------------
// Kernel 1: xp[b][t][m*64+d] = Xb[m][d] + sum_k XW[m][d][k] * x_m[b][t][k]
// ---------------------------------------------------------------------------
__global__ __launch_bounds__(256, 2)
void k1_xproj(const float* __restrict__ xa, const float* __restrict__ xv,
              const float* __restrict__ xl, const float* __restrict__ XW,
              const float* __restrict__ Xb, float* __restrict__ xp)
{
    const int m  = blockIdx.z;
    const int b  = blockIdx.y;
    const int t0 = blockIdx.x * 128;
    const float* __restrict__ xm = (m == 0) ? xa : ((m == 1) ? xv : xl);
    const int tid = threadIdx.x;
    const int q = tid >> 6;
    const int d = tid & 63;

    __shared__ __align__(16) float xs[4][256];
    __shared__ float part[4][4][64];

    DECL_W16A(XW + ((m * 64 + d) * 256 + q * 64));
    const float xbv = Xb[m * 64 + d];

    for (int g = 0; g < 32; ++g) {
        const int tb = t0 + g * 4;
        {
            const float* src = xm + ((size_t)b * S_ + tb) * D_;
            xs[0][tid] = src[0 * 256 + tid];
            xs[1][tid] = src[1 * 256 + tid];
            xs[2][tid] = src[2 * 256 + tid];
            xs[3][tid] = src[3 * 256 + tid];
        }
        __syncthreads();
        #pragma unroll
        for (int tt = 0; tt < 4; ++tt) {
            const v4f* xq = reinterpret_cast<const v4f*>(&xs[tt][q * 64]);
            float a0 = 0.f, a1 = 0.f, a2 = 0.f, a3 = 0.f;
            DOT64_V(xq);
            part[tt][q][d] = (a0 + a1) + (a2 + a3);
        }
        __syncthreads();
        {
            const int tt = q;
            float ssum = part[tt][0][d] + part[tt][1][d] + part[tt][2][d] + part[tt][3][d] + xbv;
            xp[((size_t)b * S_ + tb + tt) * MD_ + m * 64 + d] = ssum;
        }
    }
}

// ---------------------------------------------------------------------------
// Kernel 2 v5: recurrence. 32 blocks x 768 threads (12 waves), TWO lgkm-only
// barriers per step. Weights held in VGPRs via asm loads (non-remat).
// Gate tail: DPP sum-reduce (VALU) instead of shfl_xor (DS).
// ---------------------------------------------------------------------------
__global__ __launch_bounds__(768, 1)
void k2_recur(const float* __restrict__ xp, float* __restrict__ hbuf,
              const float* __restrict__ HW, const float* __restrict__ Hb,
              const float* __restrict__ CW, const float* __restrict__ W1,
              const float* __restrict__ b1, const float* __restrict__ W2,
              const float* __restrict__ b2)
{
    const int b    = blockIdx.x;
    const int tid  = threadIdx.x;
    const int w    = tid >> 6;
    const int lane = tid & 63;

    const bool is_gate = (w >= 9);
    const int  m = is_gate ? (w - 9) : (w / 3);   // gate wave g owns tgt m=g
    const int  s = is_gate ? (w - 9) : (w % 3);   // broadcast-source h segment

    __shared__ __align__(16) float hds[2][MD_];
    __shared__ float parts[12][64];

    if (tid < MD_) hds[0][tid] = 0.f;

    // ---- weights: 16 asm-pinned float4 registers per lane ----
    const float* base;
    if (!is_gate) base = (s == m) ? (HW + (m * 64 + lane) * 64)
                                  : (CW + (((m * 3 + s) * 64) + lane) * 64);
    else          base = W1 + lane * MD_ + m * 64;
    DECL_W16A(base);

    // gate-wave constants
    float hbv = 0.f, b1v = 0.f;
    float w2r0 = 0.f, w2r1 = 0.f, w2r2 = 0.f, b2v0 = 0.f, b2v1 = 0.f, b2v2 = 0.f;
    float xnext = 0.f;
    if (is_gate) {
        hbv  = Hb[m * 64 + lane];
        b1v  = b1[lane];
        w2r0 = W2[(m * 3 + 0) * 64 + lane];
        w2r1 = W2[(m * 3 + 1) * 64 + lane];
        w2r2 = W2[(m * 3 + 2) * 64 + lane];
        b2v0 = b2[m * 3 + 0]; b2v1 = b2[m * 3 + 1]; b2v2 = b2[m * 3 + 2];
        xnext = xp[((size_t)b * S_) * MD_ + m * 64 + lane];
    }
    const int s1 = (m + 1) % 3, s2 = (m + 2) % 3;
    float hist0 = 0.f, hist1 = 0.f, hist2 = 0.f, hist3 = 0.f;

    __syncthreads();

    for (int t = 0; t < S_; ++t) {
        const int cur = t & 1, nxt = cur ^ 1;

        // issue next-step x prefetch early; rides across the lgkm-only barriers
        const float xv = xnext;
        if (is_gate && (t + 1 < S_))
            xnext = xp[((size_t)b * S_ + t + 1) * MD_ + m * 64 + lane];

        // ---- phase A: every wave one 64-deep dot, weights in registers ----
        float hreg = hds[cur][s * 64 + lane];
        float a0 = 0.f, a1 = 0.f, a2 = 0.f, a3 = 0.f;
        DOT64_RL();
        parts[w][lane] = (a0 + a1) + (a2 + a3);
        BAR_LGKM();   // all partials visible

        // ---- gate wave m: tail + combine + state update, all local ----
        if (is_gate) {
            // issue LDS reads early; latency hides under tanh
            float pm  = parts[m * 3 + m][lane];
            float pc1 = parts[m * 3 + s1][lane];
            float pc2 = parts[m * 3 + s2][lane];
            float g0  = parts[9][lane];
            float g1  = parts[10][lane];
            float g2  = parts[11][lane];

            float z = fast_tanh(b1v + g0 + g1 + g2);
            float p0 = w2r0 * z, p1 = w2r1 * z, p2 = w2r2 * z;
            DPP_RED3(p0, p1, p2);   // 64-lane sums -> lane 63
            float r0 = b2v0 + rl_f32(p0, 63);
            float r1 = b2v1 + rl_f32(p1, 63);
            float r2 = b2v2 + rl_f32(p2, 63);
            // uniform softmax over this wave's own attn row (tgt = m)
            float mx  = fmaxf(r0, fmaxf(r1, r2));
            float e0  = fast_exp(r0 - mx);
            float e1  = fast_exp(r1 - mx);
            float e2  = fast_exp(r2 - mx);
            float inv = __builtin_amdgcn_rcpf(e0 + e1 + e2);
            float a1v = ((s1 == 1) ? e1 : (s1 == 2) ? e2 : e0) * inv;
            float a2v = ((s2 == 1) ? e1 : (s2 == 2) ? e2 : e0) * inv;

            float suv = xv + hbv + pm + a1v * pc1 + a2v * pc2;
            float hn  = suv * __builtin_amdgcn_rcpf(1.f + fast_exp(-suv));
            hds[nxt][m * 64 + lane] = hn;

            if      ((t & 3) == 0) hist0 = hn;
            else if ((t & 3) == 1) hist1 = hn;
            else if ((t & 3) == 2) hist2 = hn;
            else {
                hist3 = hn;
                float* dst = hbuf + ((size_t)b * S_ + (t - 3)) * MD_ + m * 64 + lane;
                dst[0 * MD_] = hist0; dst[1 * MD_] = hist1;
                dst[2 * MD_] = hist2; dst[3 * MD_] = hist3;
            }
        }
        BAR_LGKM();   // h_new visible
    }
}

// ---------------------------------------------------------------------------
// Kernel 3: out = LayerNorm(Ob + OW@h + x); OW row asm-pinned in registers.
// Reductions via DPP (result lane 63) instead of shfl_down chains.
// ---------------------------------------------------------------------------
__global__ __launch_bounds__(256, 2)
void k3_out(const float* __restrict__ xa, const float* __restrict__ xv,
            const float* __restrict__ xl, const float* __restrict__ hbuf,
            const float* __restrict__ OW, const float* __restrict__ Ob,
            const float* __restrict__ lng, const float* __restrict__ lnb,
            float* __restrict__ out)
{
    const int m  = blockIdx.z;
    const int b  = blockIdx.y;
    const int t0 = blockIdx.x * 128;
    const float* __restrict__ xm = (m == 0) ? xa : ((m == 1) ? xv : xl);
    const int k    = threadIdx.x;
    const int wv   = k >> 6;
    const int lane = k & 63;

    __shared__ __align__(16) float hs[4 * 64];
    __shared__ float psum[16], qsum[16];

    DECL_W16A(OW + (m * D_ + k) * DS_);
    const float obv = Ob[m * D_ + k];
    const float gv  = lng[m * D_ + k];
    const float bv  = lnb[m * D_ + k];

    for (int gg = 0; gg < 32; ++gg) {
        const int tb = t0 + gg * 4;
        hs[k] = hbuf[((size_t)b * S_ + tb + (k >> 6)) * MD_ + m * 64 + (k & 63)];
        __syncthreads();

        float v0, v1, v2, v3;
        {
            const v4f* h4 = reinterpret_cast<const v4f*>(&hs[0]);
            float a0 = 0.f, a1 = 0.f, a2 = 0.f, a3 = 0.f;
            DOT64_V(h4);
            v0 = obv + (a0 + a1) + (a2 + a3) + xm[((size_t)b * S_ + tb + 0) * D_ + k];
        }
        {
            const v4f* h4 = reinterpret_cast<const v4f*>(&hs[64]);
            float a0 = 0.f, a1 = 0.f, a2 = 0.f, a3 = 0.f;
            DOT64_V(h4);
            v1 = obv + (a0 + a1) + (a2 + a3) + xm[((size_t)b * S_ + tb + 1) * D_ + k];
        }
        {
            const v4f* h4 = reinterpret_cast<const v4f*>(&hs[128]);
            float a0 = 0.f, a1 = 0.f, a2 = 0.f, a3 = 0.f;
            DOT64_V(h4);
            v2 = obv + (a0 + a1) + (a2 + a3) + xm[((size_t)b * S_ + tb + 2) * D_ + k];
        }
        {
            const v4f* h4 = reinterpret_cast<const v4f*>(&hs[192]);
            float a0 = 0.f, a1 = 0.f, a2 = 0.f, a3 = 0.f;
            DOT64_V(h4);
            v3 = obv + (a0 + a1) + (a2 + a3) + xm[((size_t)b * S_ + tb + 3) * D_ + k];
        }

        float s0 = v0, s1v = v1, s2v = v2, s3 = v3;
        float q0 = v0 * v0, q1 = v1 * v1, q2 = v2 * v2, q3 = v3 * v3;
        DPP_RED4(s0, s1v, s2v, s3);
        DPP_RED4(q0, q1, q2, q3);
        if (lane == 63) {
            psum[wv * 4 + 0] = s0;  psum[wv * 4 + 1] = s1v;
            psum[wv * 4 + 2] = s2v; psum[wv * 4 + 3] = s3;
            qsum[wv * 4 + 0] = q0;  qsum[wv * 4 + 1] = q1;
            qsum[wv * 4 + 2] = q2;  qsum[wv * 4 + 3] = q3;
        }
        __syncthreads();

        const size_t obase = (size_t)m * ((size_t)B_ * S_ * D_) + ((size_t)b * S_ + tb) * D_ + k;
        {
            float ss = psum[0] + psum[4] + psum[8] + psum[12];
            float qq = qsum[0] + qsum[4] + qsum[8] + qsum[12];
            float mu = ss * (1.f / 256.f);
            float var = qq * (1.f / 256.f) - mu * mu;
            float rs = rsqrtf(var + 1e-5f);
            out[obase + 0 * D_] = (v0 - mu) * rs * gv + bv;
        }
        {
            float ss = psum[1] + psum[5] + psum[9] + psum[13];
            float qq = qsum[1] + qsum[5] + qsum[9] + qsum[13];
            float mu = ss * (1.f / 256.f);
            float var = qq * (1.f / 256.f) - mu * mu;
            float rs = rsqrtf(var + 1e-5f);
            out[obase + 1 * D_] = (v1 - mu) * rs * gv + bv;
        }
        {
            float ss = psum[2] + psum[6] + psum[10] + psum[14];
            float qq = qsum[2] + qsum[6] + qsum[10] + qsum[14];
            float mu = ss * (1.f / 256.f);
            float var = qq * (1.f / 256.f) - mu * mu;
            float rs = rsqrtf(var + 1e-5f);
            out[obase + 2 * D_] = (v2 - mu) * rs * gv + bv;
        }
        {
            float ss = psum[3] + psum[7] + psum[11] + psum[15];
            float qq = qsum[3] + qsum[7] + qsum[11] + qsum[15];
            float mu = ss * (1.f / 256.f);
            float var = qq * (1.f / 256.f) - mu * mu;
            float rs = rsqrtf(var + 1e-5f);
            out[obase + 3 * D_] = (v3 - mu) * rs * gv + bv;
        }
    }
}

extern "C" void kernel_launch(void* const* d_in, const int* in_sizes, int n_in,
                              void* d_out, int out_size, void* d_ws, size_t ws_size,
                              hipStream_t stream)
{
    const float* xa  = (const float*)d_in[0];
    const float* xv  = (const float*)d_in[1];
    const float* xl  = (const float*)d_in[2];
    const float* XW  = (const float*)d_in[3];
    const float* Xb  = (const float*)d_in[4];
    const float* HW  = (const float*)d_in[5];
    const float* Hb  = (const float*)d_in[6];
    const float* OW  = (const float*)d_in[7];
    const float* Ob  = (const float*)d_in[8];
    const float* CW  = (const float*)d_in[9];
    const float* W1  = (const float*)d_in[10];
    const float* b1  = (const float*)d_in[11];
    const float* W2  = (const float*)d_in[12];
    const float* b2  = (const float*)d_in[13];
    const float* lng = (const float*)d_in[14];
    const float* lnb = (const float*)d_in[15];
    float* out = (float*)d_out;

    float* xp = (float*)d_ws;                          // [B][S][192]
    float* hb = xp + (size_t)B_ * S_ * MD_;            // [B][S][192]

    k1_xproj<<<dim3(8, 32, 3), 256, 0, stream>>>(xa, xv, xl, XW, Xb, xp);
    k2_recur<<<dim3(32), 768, 0, stream>>>(xp, hb, HW, Hb, CW, W1, b1, W2, b2);
    k3_out  <<<dim3(8, 32, 3), 256, 0, stream>>>(xa, xv, xl, hb, OW, Ob, lng, lnb, out);
}

// Round 3
// 1239.174 us; speedup vs baseline: 2.0867x; 1.0805x over previous
//
#include <hip/hip_runtime.h>
#include <math.h>

#define B_  32
#define S_  1024
#define D_  256
#define DS_ 64
#define M_  3
#define MD_ 192   // M*DS

// lgkmcnt-only barrier: LDS visibility without draining vmcnt (keeps global
// prefetch loads / result stores in flight across recurrence steps).
#define BAR_LGKM() asm volatile("s_waitcnt lgkmcnt(0)\n\ts_barrier" ::: "memory")

__device__ __forceinline__ float rl_f32(float v, int lane) {
    return __uint_as_float(__builtin_amdgcn_readlane(__float_as_uint(v), lane));
}

#define L2E_ 1.4426950408889634f
__device__ __forceinline__ float fast_exp(float x) { return exp2f(x * L2E_); }
// tanh(x) = 1 - 2/(exp2(2*log2e*x)+1); inf-safe at both ends.
__device__ __forceinline__ float fast_tanh(float x) {
    float t = exp2f(x * (2.0f * L2E_));
    return 1.0f - 2.0f * __builtin_amdgcn_rcpf(t + 1.0f);
}

typedef float v4f __attribute__((ext_vector_type(4)));

// ---- weight block: 16 float4 loaded via ASM so they are NOT rematerializable
// (round-1 lesson: plain loads -> compiler re-loads them every iteration).
#define ALD4(dst, p, off) \
    asm volatile("global_load_dwordx4 %0, %1, off offset:" #off \
                 : "=v"(dst) : "v"(p))

#define DECL_W16A(baseptr) \
    v4f W00, W01, W02, W03, W04, W05, W06, W07, \
        W08, W09, W10, W11, W12, W13, W14, W15; \
    { const float* _wp = (baseptr); \
      ALD4(W00, _wp, 0);   ALD4(W01, _wp, 16);  ALD4(W02, _wp, 32);  ALD4(W03, _wp, 48);  \
      ALD4(W04, _wp, 64);  ALD4(W05, _wp, 80);  ALD4(W06, _wp, 96);  ALD4(W07, _wp, 112); \
      ALD4(W08, _wp, 128); ALD4(W09, _wp, 144); ALD4(W10, _wp, 160); ALD4(W11, _wp, 176); \
      ALD4(W12, _wp, 192); ALD4(W13, _wp, 208); ALD4(W14, _wp, 224); ALD4(W15, _wp, 240); \
      asm volatile("s_waitcnt vmcnt(0)" ::: "memory"); }

// ---- 64-deep dot: 16 v4f (LDS, wave-uniform broadcast reads) x 16 weight
// v4f, accumulated as packed fp32 (v_pk_fma_f32: 2 MACs/inst) in 4 chains.
// Replaces DOT64_RL (64 readlane + 64 scalar fma + VALU->SGPR hazards).
#define DOT64_PKV(h4, out) { \
    v4f A0 = W00 * (h4)[0]; \
    v4f A1 = W01 * (h4)[1]; \
    v4f A2 = W02 * (h4)[2]; \
    v4f A3 = W03 * (h4)[3]; \
    A0 = __builtin_elementwise_fma(W04, (h4)[4],  A0); \
    A1 = __builtin_elementwise_fma(W05, (h4)[5],  A1); \
    A2 = __builtin_elementwise_fma(W06, (h4)[6],  A2); \
    A3 = __builtin_elementwise_fma(W07, (h4)[7],  A3); \
    A0 = __builtin_elementwise_fma(W08, (h4)[8],  A0); \
    A1 = __builtin_elementwise_fma(W09, (h4)[9],  A1); \
    A2 = __builtin_elementwise_fma(W10, (h4)[10], A2); \
    A3 = __builtin_elementwise_fma(W11, (h4)[11], A3); \
    A0 = __builtin_elementwise_fma(W12, (h4)[12], A0); \
    A1 = __builtin_elementwise_fma(W13, (h4)[13], A1); \
    A2 = __builtin_elementwise_fma(W14, (h4)[14], A2); \
    A3 = __builtin_elementwise_fma(W15, (h4)[15], A3); \
    v4f T = (A0 + A1) + (A2 + A3); \
    out = (T.x + T.y) + (T.z + T.w); \
}

// ---- canonical GCN full-wave (64-lane) sum reduce via DPP; result lane 63.
#define DPP_RED3(A, Bv, C) asm volatile( \
    "v_add_f32 %0, %0, %0 row_shr:1 bound_ctrl:0\n\t" \
    "v_add_f32 %1, %1, %1 row_shr:1 bound_ctrl:0\n\t" \
    "v_add_f32 %2, %2, %2 row_shr:1 bound_ctrl:0\n\t" \
    "v_add_f32 %0, %0, %0 row_shr:2 bound_ctrl:0\n\t" \
    "v_add_f32 %1, %1, %1 row_shr:2 bound_ctrl:0\n\t" \
    "v_add_f32 %2, %2, %2 row_shr:2 bound_ctrl:0\n\t" \
    "v_add_f32 %0, %0, %0 row_shr:4 bound_ctrl:0\n\t" \
    "v_add_f32 %1, %1, %1 row_shr:4 bound_ctrl:0\n\t" \
    "v_add_f32 %2, %2, %2 row_shr:4 bound_ctrl:0\n\t" \
    "v_add_f32 %0, %0, %0 row_shr:8 bound_ctrl:0\n\t" \
    "v_add_f32 %1, %1, %1 row_shr:8 bound_ctrl:0\n\t" \
    "v_add_f32 %2, %2, %2 row_shr:8 bound_ctrl:0\n\t" \
    "v_add_f32 %0, %0, %0 row_bcast:15 row_mask:0xa\n\t" \
    "v_add_f32 %1, %1, %1 row_bcast:15 row_mask:0xa\n\t" \
    "v_add_f32 %2, %2, %2 row_bcast:15 row_mask:0xa\n\t" \
    "v_add_f32 %0, %0, %0 row_bcast:31 row_mask:0xc\n\t" \
    "v_add_f32 %1, %1, %1 row_bcast:31 row_mask:0xc\n\t" \
    "v_add_f32 %2, %2, %2 row_bcast:31 row_mask:0xc" \
    : "+v"(A), "+v"(Bv), "+v"(C))

#define DPP_RED4(A, Bv, C, Dv) asm volatile( \
    "v_add_f32 %0, %0, %0 row_shr:1 bound_ctrl:0\n\t" \
    "v_add_f32 %1, %1, %1 row_shr:1 bound_ctrl:0\n\t" \
    "v_add_f32 %2, %2, %2 row_shr:1 bound_ctrl:0\n\t" \
    "v_add_f32 %3, %3, %3 row_shr:1 bound_ctrl:0\n\t" \
    "v_add_f32 %0, %0, %0 row_shr:2 bound_ctrl:0\n\t" \
    "v_add_f32 %1, %1, %1 row_shr:2 bound_ctrl:0\n\t" \
    "v_add_f32 %2, %2, %2 row_shr:2 bound_ctrl:0\n\t" \
    "v_add_f32 %3, %3, %3 row_shr:2 bound_ctrl:0\n\t" \
    "v_add_f32 %0, %0, %0 row_shr:4 bound_ctrl:0\n\t" \
    "v_add_f32 %1, %1, %1 row_shr:4 bound_ctrl:0\n\t" \
    "v_add_f32 %2, %2, %2 row_shr:4 bound_ctrl:0\n\t" \
    "v_add_f32 %3, %3, %3 row_shr:4 bound_ctrl:0\n\t" \
    "v_add_f32 %0, %0, %0 row_shr:8 bound_ctrl:0\n\t" \
    "v_add_f32 %1, %1, %1 row_shr:8 bound_ctrl:0\n\t" \
    "v_add_f32 %2, %2, %2 row_shr:8 bound_ctrl:0\n\t" \
    "v_add_f32 %3, %3, %3 row_shr:8 bound_ctrl:0\n\t" \
    "v_add_f32 %0, %0, %0 row_bcast:15 row_mask:0xa\n\t" \
    "v_add_f32 %1, %1, %1 row_bcast:15 row_mask:0xa\n\t" \
    "v_add_f32 %2, %2, %2 row_bcast:15 row_mask:0xa\n\t" \
    "v_add_f32 %3, %3, %3 row_bcast:15 row_mask:0xa\n\t" \
    "v_add_f32 %0, %0, %0 row_bcast:31 row_mask:0xc\n\t" \
    "v_add_f32 %1, %1, %1 row_bcast:31 row_mask:0xc\n\t" \
    "v_add_f32 %2, %2, %2 row_bcast:31 row_mask:0xc\n\t" \
    "v_add_f32 %3, %3, %3 row_bcast:31 row_mask:0xc" \
    : "+v"(A), "+v"(Bv), "+v"(C), "+v"(Dv))

// ---------------------------------------------------------------------------
// Kernel 1: xp[b][t][m*64+d] = Xb[m][d] + sum_k XW[m][d][k] * x_m[b][t][k]
// ---------------------------------------------------------------------------
__global__ __launch_bounds__(256, 2)
void k1_xproj(const float* __restrict__ xa, const float* __restrict__ xv,
              const float* __restrict__ xl, const float* __restrict__ XW,
              const float* __restrict__ Xb, float* __restrict__ xp)
{
    const int m  = blockIdx.z;
    const int b  = blockIdx.y;
    const int t0 = blockIdx.x * 128;
    const float* __restrict__ xm = (m == 0) ? xa : ((m == 1) ? xv : xl);
    const int tid = threadIdx.x;
    const int q = tid >> 6;
    const int d = tid & 63;

    __shared__ __align__(16) float xs[1024];
    __shared__ float part[4][4][64];

    DECL_W16A(XW + ((m * 64 + d) * 256 + q * 64));
    const float xbv = Xb[m * 64 + d];

    for (int g = 0; g < 32; ++g) {
        const int tb = t0 + g * 4;
        // 4 rows (1024 floats) staged as one dwordx4 per thread
        reinterpret_cast<v4f*>(xs)[tid] =
            reinterpret_cast<const v4f*>(xm + ((size_t)b * S_ + tb) * D_)[tid];
        __syncthreads();
        #pragma unroll
        for (int tt = 0; tt < 4; ++tt) {
            const v4f* xq = reinterpret_cast<const v4f*>(&xs[tt * 256 + q * 64]);
            float accv;
            DOT64_PKV(xq, accv);
            part[tt][q][d] = accv;
        }
        __syncthreads();
        {
            const int tt = q;
            float ssum = part[tt][0][d] + part[tt][1][d] + part[tt][2][d] + part[tt][3][d] + xbv;
            xp[((size_t)b * S_ + tb + tt) * MD_ + m * 64 + d] = ssum;
        }
    }
}

// ---------------------------------------------------------------------------
// Kernel 2 v6: recurrence. 32 blocks x 768 threads (12 waves), TWO lgkm-only
// barriers per step. Weights in VGPRs (asm, non-remat). Phase-A dot reads h
// via wave-uniform LDS broadcast (16 x ds_read_b128) and accumulates with
// packed fp32 fma -- no readlane, no VALU->SGPR hazards.
// ---------------------------------------------------------------------------
__global__ __launch_bounds__(768, 1)
void k2_recur(const float* __restrict__ xp, float* __restrict__ hbuf,
              const float* __restrict__ HW, const float* __restrict__ Hb,
              const float* __restrict__ CW, const float* __restrict__ W1,
              const float* __restrict__ b1, const float* __restrict__ W2,
              const float* __restrict__ b2)
{
    const int b    = blockIdx.x;
    const int tid  = threadIdx.x;
    const int w    = tid >> 6;
    const int lane = tid & 63;

    const bool is_gate = (w >= 9);
    const int  m = is_gate ? (w - 9) : (w / 3);   // gate wave g owns tgt m=g
    const int  s = is_gate ? (w - 9) : (w % 3);   // source h segment

    __shared__ __align__(16) float hds[2][MD_];
    __shared__ float parts[12][64];

    if (tid < MD_) hds[0][tid] = 0.f;

    // ---- weights: 16 asm-pinned float4 registers per lane ----
    const float* base;
    if (!is_gate) base = (s == m) ? (HW + (m * 64 + lane) * 64)
                                  : (CW + (((m * 3 + s) * 64) + lane) * 64);
    else          base = W1 + lane * MD_ + m * 64;
    DECL_W16A(base);

    // gate-wave constants
    float hbv = 0.f, b1v = 0.f;
    float w2r0 = 0.f, w2r1 = 0.f, w2r2 = 0.f, b2v0 = 0.f, b2v1 = 0.f, b2v2 = 0.f;
    float xnext = 0.f;
    if (is_gate) {
        hbv  = Hb[m * 64 + lane];
        b1v  = b1[lane];
        w2r0 = W2[(m * 3 + 0) * 64 + lane];
        w2r1 = W2[(m * 3 + 1) * 64 + lane];
        w2r2 = W2[(m * 3 + 2) * 64 + lane];
        b2v0 = b2[m * 3 + 0]; b2v1 = b2[m * 3 + 1]; b2v2 = b2[m * 3 + 2];
        xnext = xp[((size_t)b * S_) * MD_ + m * 64 + lane];
    }
    const int s1 = (m + 1) % 3, s2 = (m + 2) % 3;
    float hist0 = 0.f, hist1 = 0.f, hist2 = 0.f, hist3 = 0.f;

    __syncthreads();

    for (int t = 0; t < S_; ++t) {
        const int cur = t & 1, nxt = cur ^ 1;

        // issue next-step x prefetch early; rides across the lgkm-only barriers
        const float xv = xnext;
        if (is_gate && (t + 1 < S_))
            xnext = xp[((size_t)b * S_ + t + 1) * MD_ + m * 64 + lane];

        // ---- phase A: 64-deep dot, h broadcast from LDS, packed fma ----
        const v4f* h4 = reinterpret_cast<const v4f*>(&hds[cur][s * 64]);
        float accv;
        DOT64_PKV(h4, accv);
        parts[w][lane] = accv;
        BAR_LGKM();   // all partials visible

        // ---- gate wave m: tail + combine + state update, all local ----
        if (is_gate) {
            // own gate part (accv) stays in reg; read the rest per-lane
            float pm  = parts[m * 3 + m][lane];
            float pc1 = parts[m * 3 + s1][lane];
            float pc2 = parts[m * 3 + s2][lane];
            float go1 = parts[9 + s1][lane];
            float go2 = parts[9 + s2][lane];

            float z = fast_tanh(b1v + accv + go1 + go2);
            float p0 = w2r0 * z, p1 = w2r1 * z, p2 = w2r2 * z;
            DPP_RED3(p0, p1, p2);   // 64-lane sums -> lane 63
            float r0 = b2v0 + rl_f32(p0, 63);
            float r1 = b2v1 + rl_f32(p1, 63);
            float r2 = b2v2 + rl_f32(p2, 63);
            // uniform softmax over this wave's own attn row (tgt = m)
            float mx  = fmaxf(r0, fmaxf(r1, r2));
            float e0  = fast_exp(r0 - mx);
            float e1  = fast_exp(r1 - mx);
            float e2  = fast_exp(r2 - mx);
            float inv = __builtin_amdgcn_rcpf(e0 + e1 + e2);
            float a1v = ((s1 == 1) ? e1 : (s1 == 2) ? e2 : e0) * inv;
            float a2v = ((s2 == 1) ? e1 : (s2 == 2) ? e2 : e0) * inv;

            float suv = xv + hbv + pm + a1v * pc1 + a2v * pc2;
            float hn  = suv * __builtin_amdgcn_rcpf(1.f + fast_exp(-suv));
            hds[nxt][m * 64 + lane] = hn;

            if      ((t & 3) == 0) hist0 = hn;
            else if ((t & 3) == 1) hist1 = hn;
            else if ((t & 3) == 2) hist2 = hn;
            else {
                hist3 = hn;
                float* dst = hbuf + ((size_t)b * S_ + (t - 3)) * MD_ + m * 64 + lane;
                dst[0 * MD_] = hist0; dst[1 * MD_] = hist1;
                dst[2 * MD_] = hist2; dst[3 * MD_] = hist3;
            }
        }
        BAR_LGKM();   // h_new visible
    }
}

// ---------------------------------------------------------------------------
// Kernel 3: out = LayerNorm(Ob + OW@h + x); OW row asm-pinned in registers.
// Dots via packed fp32 fma; reductions via DPP (result lane 63).
// ---------------------------------------------------------------------------
__global__ __launch_bounds__(256, 2)
void k3_out(const float* __restrict__ xa, const float* __restrict__ xv,
            const float* __restrict__ xl, const float* __restrict__ hbuf,
            const float* __restrict__ OW, const float* __restrict__ Ob,
            const float* __restrict__ lng, const float* __restrict__ lnb,
            float* __restrict__ out)
{
    const int m  = blockIdx.z;
    const int b  = blockIdx.y;
    const int t0 = blockIdx.x * 128;
    const float* __restrict__ xm = (m == 0) ? xa : ((m == 1) ? xv : xl);
    const int k    = threadIdx.x;
    const int wv   = k >> 6;
    const int lane = k & 63;

    __shared__ __align__(16) float hs[4 * 64];
    __shared__ float psum[16], qsum[16];

    DECL_W16A(OW + (m * D_ + k) * DS_);
    const float obv = Ob[m * D_ + k];
    const float gv  = lng[m * D_ + k];
    const float bv  = lnb[m * D_ + k];

    for (int gg = 0; gg < 32; ++gg) {
        const int tb = t0 + gg * 4;
        hs[k] = hbuf[((size_t)b * S_ + tb + (k >> 6)) * MD_ + m * 64 + (k & 63)];
        __syncthreads();

        float v0, v1, v2, v3;
        {
            const v4f* h4 = reinterpret_cast<const v4f*>(&hs[0]);
            float accv; DOT64_PKV(h4, accv);
            v0 = obv + accv + xm[((size_t)b * S_ + tb + 0) * D_ + k];
        }
        {
            const v4f* h4 = reinterpret_cast<const v4f*>(&hs[64]);
            float accv; DOT64_PKV(h4, accv);
            v1 = obv + accv + xm[((size_t)b * S_ + tb + 1) * D_ + k];
        }
        {
            const v4f* h4 = reinterpret_cast<const v4f*>(&hs[128]);
            float accv; DOT64_PKV(h4, accv);
            v2 = obv + accv + xm[((size_t)b * S_ + tb + 2) * D_ + k];
        }
        {
            const v4f* h4 = reinterpret_cast<const v4f*>(&hs[192]);
            float accv; DOT64_PKV(h4, accv);
            v3 = obv + accv + xm[((size_t)b * S_ + tb + 3) * D_ + k];
        }

        float s0 = v0, s1v = v1, s2v = v2, s3 = v3;
        float q0 = v0 * v0, q1 = v1 * v1, q2 = v2 * v2, q3 = v3 * v3;
        DPP_RED4(s0, s1v, s2v, s3);
        DPP_RED4(q0, q1, q2, q3);
        if (lane == 63) {
            psum[wv * 4 + 0] = s0;  psum[wv * 4 + 1] = s1v;
            psum[wv * 4 + 2] = s2v; psum[wv * 4 + 3] = s3;
            qsum[wv * 4 + 0] = q0;  qsum[wv * 4 + 1] = q1;
            qsum[wv * 4 + 2] = q2;  qsum[wv * 4 + 3] = q3;
        }
        __syncthreads();

        const size_t obase = (size_t)m * ((size_t)B_ * S_ * D_) + ((size_t)b * S_ + tb) * D_ + k;
        {
            float ss = psum[0] + psum[4] + psum[8] + psum[12];
            float qq = qsum[0] + qsum[4] + qsum[8] + qsum[12];
            float mu = ss * (1.f / 256.f);
            float var = qq * (1.f / 256.f) - mu * mu;
            float rs = rsqrtf(var + 1e-5f);
            out[obase + 0 * D_] = (v0 - mu) * rs * gv + bv;
        }
        {
            float ss = psum[1] + psum[5] + psum[9] + psum[13];
            float qq = qsum[1] + qsum[5] + qsum[9] + qsum[13];
            float mu = ss * (1.f / 256.f);
            float var = qq * (1.f / 256.f) - mu * mu;
            float rs = rsqrtf(var + 1e-5f);
            out[obase + 1 * D_] = (v1 - mu) * rs * gv + bv;
        }
        {
            float ss = psum[2] + psum[6] + psum[10] + psum[14];
            float qq = qsum[2] + qsum[6] + qsum[10] + qsum[14];
            float mu = ss * (1.f / 256.f);
            float var = qq * (1.f / 256.f) - mu * mu;
            float rs = rsqrtf(var + 1e-5f);
            out[obase + 2 * D_] = (v2 - mu) * rs * gv + bv;
        }
        {
            float ss = psum[3] + psum[7] + psum[11] + psum[15];
            float qq = qsum[3] + qsum[7] + qsum[11] + qsum[15];
            float mu = ss * (1.f / 256.f);
            float var = qq * (1.f / 256.f) - mu * mu;
            float rs = rsqrtf(var + 1e-5f);
            out[obase + 3 * D_] = (v3 - mu) * rs * gv + bv;
        }
    }
}

extern "C" void kernel_launch(void* const* d_in, const int* in_sizes, int n_in,
                              void* d_out, int out_size, void* d_ws, size_t ws_size,
                              hipStream_t stream)
{
    const float* xa  = (const float*)d_in[0];
    const float* xv  = (const float*)d_in[1];
    const float* xl  = (const float*)d_in[2];
    const float* XW  = (const float*)d_in[3];
    const float* Xb  = (const float*)d_in[4];
    const float* HW  = (const float*)d_in[5];
    const float* Hb  = (const float*)d_in[6];
    const float* OW  = (const float*)d_in[7];
    const float* Ob  = (const float*)d_in[8];
    const float* CW  = (const float*)d_in[9];
    const float* W1  = (const float*)d_in[10];
    const float* b1  = (const float*)d_in[11];
    const float* W2  = (const float*)d_in[12];
    const float* b2  = (const float*)d_in[13];
    const float* lng = (const float*)d_in[14];
    const float* lnb = (const float*)d_in[15];
    float* out = (float*)d_out;

    float* xp = (float*)d_ws;                          // [B][S][192]
    float* hb = xp + (size_t)B_ * S_ * MD_;            // [B][S][192]

    k1_xproj<<<dim3(8, 32, 3), 256, 0, stream>>>(xa, xv, xl, XW, Xb, xp);
    k2_recur<<<dim3(32), 768, 0, stream>>>(xp, hb, HW, Hb, CW, W1, b1, W2, b2);
    k3_out  <<<dim3(8, 32, 3), 256, 0, stream>>>(xa, xv, xl, hb, OW, Ob, lng, lnb, out);
}